// Round 2
// baseline (155.200 us; speedup 1.0000x reference)
//
#include <hip/hip_runtime.h>
#include <hip/hip_bf16.h>

#define KDIM 256
#define NTOT 131072
#define PN   65536      // 256*256
#define NB   256        // split-K blocks
#define RPB  512        // rows per block = NTOT/NB
#define NCH  16         // chunks per block = RPB/32
#define CH   (32*KDIM)  // floats per chunk per matrix

typedef float f32x4 __attribute__((ext_vector_type(4)));
typedef __bf16 bf16x8 __attribute__((ext_vector_type(8)));

__device__ __forceinline__ unsigned short f2bf(float x){
  unsigned u = __float_as_uint(x);
  u += 0x7fffu + ((u >> 16) & 1u);   // round-to-nearest-even
  return (unsigned short)(u >> 16);
}
__device__ __forceinline__ unsigned pk2(float lo, float hi){
  return (unsigned)f2bf(lo) | ((unsigned)f2bf(hi) << 16);
}
__device__ __forceinline__ float bf2f(unsigned short u){
  return __uint_as_float((unsigned)u << 16);
}
// XOR swizzle on byte-bits 4..6 of a 64B-row layout
__device__ __forceinline__ int swz(int i){ return (((i >> 1) ^ (i >> 4)) & 7) << 4; }

struct Stage { f32x4 a0, a1, b0, b1; };

__device__ __forceinline__ void stage_load(Stage& s, const float* pa, const float* pb, long off){
  s.a0 = *(const f32x4*)(pa + off);
  s.a1 = *(const f32x4*)(pa + off + KDIM);
  s.b0 = *(const f32x4*)(pb + off);
  s.b1 = *(const f32x4*)(pb + off + KDIM);
}

__device__ __forceinline__ void stage_store(const Stage& s, char* As, char* Bs, const int* offW){
#pragma unroll
  for (int m = 0; m < 4; ++m){
    *(unsigned*)(As + offW[m]) = pk2(s.a0[m], s.a1[m]);
    *(unsigned*)(Bs + offW[m]) = pk2(s.b0[m], s.b1[m]);
  }
}

__device__ __forceinline__ void compute_t(const char* As, const char* Bs,
                                          const int* offA, const int* offB,
                                          f32x4 (&acc)[4][4])
{
  bf16x8 af[4], bfr[4];
#pragma unroll
  for (int m = 0; m < 4; ++m) af[m]  = *(const bf16x8*)(As + offA[m]);
#pragma unroll
  for (int n = 0; n < 4; ++n) bfr[n] = *(const bf16x8*)(Bs + offB[n]);
#pragma unroll
  for (int m = 0; m < 4; ++m)
#pragma unroll
    for (int n = 0; n < 4; ++n)
      acc[m][n] = __builtin_amdgcn_mfma_f32_16x16x32_bf16(af[m], bfr[n], acc[m][n], 0, 0, 0);
}

// K1: partial_b[256][256] (bf16) = sum over this block's 512-row N-chunk of v1[n][i]*v2[n][j]
__global__ __launch_bounds__(1024, 3) void k_gemm(const float* __restrict__ v1,
                                                  const float* __restrict__ v2,
                                                  unsigned short* __restrict__ part)
{
  __shared__ char sm[65536];   // buf0: A@0 B@16K ; buf1: A@32K B@48K  (BK=32, rows=64B)
  const int t    = threadIdx.x;
  const int b    = blockIdx.x;
  const int lane = t & 63, wid = t >> 6;
  const int di   = lane & 15, g = lane >> 4;
  const int wr   = wid >> 2, wc = wid & 3;
  const int i0   = wr * 64, j0 = wc * 64;   // 4x4 waves, 64x64 tile each
  const int rp   = wid;                     // staging: wave = row-pair of chunk
  const int c0   = lane * 4;                // 4-col group

  int offW[4], offA[4], offB[4];
#pragma unroll
  for (int m = 0; m < 4; ++m){ int i = c0 + m;         offW[m] = ((i << 6) + (rp << 2)) ^ swz(i); }
#pragma unroll
  for (int m = 0; m < 4; ++m){ int i = i0 + 16*m + di; offA[m] = ((i << 6) + (g << 4)) ^ swz(i); }
#pragma unroll
  for (int n = 0; n < 4; ++n){ int j = j0 + 16*n + di; offB[n] = ((j << 6) + (g << 4)) ^ swz(j); }

  f32x4 acc[4][4];
#pragma unroll
  for (int m = 0; m < 4; ++m)
#pragma unroll
    for (int n = 0; n < 4; ++n){ f32x4 z = {0.f,0.f,0.f,0.f}; acc[m][n] = z; }

  const long rowBase = (long)b * RPB;
  const float* pa = v1 + (rowBase + 2*rp) * KDIM + c0;
  const float* pb = v2 + (rowBase + 2*rp) * KDIM + c0;

  Stage sE, sO;                      // even-chunk / odd-chunk register sets
  stage_load(sE, pa, pb, 0);
  stage_load(sO, pa, pb, CH);
  stage_store(sE, sm, sm + 16384, offW);
  __syncthreads();

#pragma unroll 2
  for (int c = 0; c < NCH; ++c){
    const int cb = c & 1;
    char* Ac = sm + cb * 32768;        char* Bc = Ac + 16384;
    char* An = sm + (cb ^ 1) * 32768;  char* Bn = An + 16384;
    if (c + 2 < NCH){                         // issue loads for chunk c+2 first
      Stage& ld = cb ? sO : sE;               // (c+2)&1 == c&1
      stage_load(ld, pa, pb, (long)(c + 2) * CH);
    }
    if (c + 1 < NCH){                         // store chunk c+1 (vmcnt leaves c+2 in flight)
      Stage& st = cb ? sE : sO;
      stage_store(st, An, Bn, offW);
    }
    compute_t(Ac, Bc, offA, offB, acc);
    __syncthreads();                          // one barrier per chunk
  }

  unsigned short* op = part + (size_t)b * PN;
#pragma unroll
  for (int m = 0; m < 4; ++m)
#pragma unroll
    for (int n = 0; n < 4; ++n){
      const int i = i0 + 16*m + 4*g;
      const int j = j0 + 16*n + di;
#pragma unroll
      for (int r = 0; r < 4; ++r)
        op[(size_t)(i + r) * KDIM + j] = f2bf(acc[m][n][r]);
    }
}

// K2: P = sum_b part_b ; row sums r[gr] and (atomic) col sums c[j]
__global__ __launch_bounds__(1024) void k_reduce(const unsigned short* __restrict__ part,
                                                 float* __restrict__ P,
                                                 float* __restrict__ rsum,
                                                 float* __restrict__ csum)
{
  __shared__ float red[1024];
  const int gr = blockIdx.x;            // P row
  const int t  = threadIdx.x;
  const int j  = t & 255, q = t >> 8;   // 4-way split over partial buffers
  const int bpq = NB >> 2;
  float s = 0.f;
  const unsigned short* p = part + (size_t)(q * bpq) * PN + gr * KDIM + j;
  for (int b = 0; b < bpq; ++b) s += bf2f(p[(size_t)b * PN]);
  red[t] = s; __syncthreads();
  if (t < 512) red[t] += red[t + 512];
  __syncthreads();
  float v = 0.f;
  if (t < 256){
    v = red[t] + red[t + 256];
    P[gr * KDIM + t] = v;
    atomicAdd(&csum[t], v);
  }
  __syncthreads();
  red[t] = (t < 256) ? v : 0.f;
  __syncthreads();
  for (int st = 128; st > 0; st >>= 1){
    if (t < st) red[t] += red[t + st];
    __syncthreads();
  }
  if (t == 0) rsum[gr] = red[0];
}

// K3: S = sum r ; lm[i] = log((r_i + c_i)/(2S)) ; scal[0] = 1/(2S)
__global__ __launch_bounds__(256) void k_marg(const float* __restrict__ rsum,
                                              const float* __restrict__ csum,
                                              float* __restrict__ lm,
                                              float* __restrict__ scal)
{
  __shared__ float red[256];
  const int i = threadIdx.x;
  float ri = rsum[i];
  red[i] = ri; __syncthreads();
  for (int st = 128; st > 0; st >>= 1){
    if (i < st) red[i] += red[i + st];
    __syncthreads();
  }
  const float S = red[0];
  const float inv2S = 0.5f / S;
  float mi = (ri + csum[i]) * inv2S;
  mi = fmaxf(mi, 2.220446049250313e-16f);
  lm[i] = logf(mi);
  if (i == 0) scal[0] = inv2S;
}

// K4: loss = sum_ij -q*(log q - 10*(lm_i + lm_j)),  q = (P_ij + P_ji)/(2S)
__global__ __launch_bounds__(1024) void k_loss(const float* __restrict__ P,
                                               const float* __restrict__ lm,
                                               const float* __restrict__ scal,
                                               float* __restrict__ out)
{
  __shared__ float red[1024];
  const float inv2S = scal[0];
  float acc = 0.f;
  for (int e = threadIdx.x; e < PN; e += 1024){
    const int i = e >> 8, j = e & 255;
    float q = (P[i * KDIM + j] + P[j * KDIM + i]) * inv2S;
    q = fmaxf(q, 2.220446049250313e-16f);
    acc += -q * (logf(q) - 10.0f * (lm[i] + lm[j]));
  }
  red[threadIdx.x] = acc; __syncthreads();
  for (int st = 512; st > 0; st >>= 1){
    if (threadIdx.x < st) red[threadIdx.x] += red[threadIdx.x + st];
    __syncthreads();
  }
  if (threadIdx.x == 0) out[0] = red[0];
}

extern "C" void kernel_launch(void* const* d_in, const int* in_sizes, int n_in,
                              void* d_out, int out_size, void* d_ws, size_t ws_size,
                              hipStream_t stream) {
  const float* v1 = (const float*)d_in[0];
  const float* v2 = (const float*)d_in[1];
  float* out = (float*)d_out;
  char*  wsc = (char*)d_ws;

  unsigned short* part = (unsigned short*)wsc;                 // NB*PN bf16 = 32 MB
  float* P    = (float*)(wsc + (size_t)NB * PN * 2);           // 256 KB
  float* rsum = P + PN;
  float* csum = rsum + 256;
  float* lm   = csum + 256;
  float* scal = lm + 256;

  hipMemsetAsync(csum, 0, 256 * sizeof(float), stream);
  k_gemm  <<<NB, 1024, 0, stream>>>(v1, v2, part);
  k_reduce<<<256, 1024, 0, stream>>>(part, P, rsum, csum);
  k_marg  <<<1, 256, 0, stream>>>(rsum, csum, lm, scal);
  k_loss  <<<1, 1024, 0, stream>>>(P, lm, scal, out);
}

// Round 3
// 105.483 us; speedup vs baseline: 1.4713x; 1.4713x over previous
//
#include <hip/hip_runtime.h>
#include <hip/hip_bf16.h>

#define KDIM 256
#define NTOT 131072
#define PN   65536      // 256*256
#define NB   256        // split-K blocks
#define RPB  512        // rows per block = NTOT/NB
#define NCH  16         // chunks per block = RPB/32
#define CH   (32*KDIM)  // floats per chunk per matrix

typedef float f32x4 __attribute__((ext_vector_type(4)));
typedef __bf16 bf16x8 __attribute__((ext_vector_type(8)));

__device__ __forceinline__ unsigned short f2bf(float x){
  unsigned u = __float_as_uint(x);
  u += 0x7fffu + ((u >> 16) & 1u);   // round-to-nearest-even
  return (unsigned short)(u >> 16);
}
__device__ __forceinline__ unsigned pk2(float lo, float hi){
  return (unsigned)f2bf(lo) | ((unsigned)f2bf(hi) << 16);
}
__device__ __forceinline__ float bf2f(unsigned short u){
  return __uint_as_float((unsigned)u << 16);
}
// XOR swizzle on byte-bits 4..6 of a 64B-row layout
__device__ __forceinline__ int swz(int i){ return (((i >> 1) ^ (i >> 4)) & 7) << 4; }

// LDS-only barrier: waits ds ops (lgkm) but lets global loads stay in flight
// across the barrier (avoids the compiler's vmcnt(0) drain before s_barrier).
__device__ __forceinline__ void lds_barrier(){
  asm volatile("s_waitcnt lgkmcnt(0)\n\ts_barrier" ::: "memory");
}

struct Stage { f32x4 a0, a1, b0, b1; };

__device__ __forceinline__ void stage_load(Stage& s, const float* pa, const float* pb, long off){
  s.a0 = *(const f32x4*)(pa + off);
  s.a1 = *(const f32x4*)(pa + off + KDIM);
  s.b0 = *(const f32x4*)(pb + off);
  s.b1 = *(const f32x4*)(pb + off + KDIM);
}

__device__ __forceinline__ void stage_store(const Stage& s, char* As, char* Bs, const int* offW){
#pragma unroll
  for (int m = 0; m < 4; ++m){
    *(unsigned*)(As + offW[m]) = pk2(s.a0[m], s.a1[m]);
    *(unsigned*)(Bs + offW[m]) = pk2(s.b0[m], s.b1[m]);
  }
}

__device__ __forceinline__ void compute_t(const char* As, const char* Bs,
                                          const int* offA, const int* offB,
                                          f32x4 (&acc)[4][4])
{
  bf16x8 af[4], bfr[4];
#pragma unroll
  for (int m = 0; m < 4; ++m) af[m]  = *(const bf16x8*)(As + offA[m]);
#pragma unroll
  for (int n = 0; n < 4; ++n) bfr[n] = *(const bf16x8*)(Bs + offB[n]);
#pragma unroll
  for (int m = 0; m < 4; ++m)
#pragma unroll
    for (int n = 0; n < 4; ++n)
      acc[m][n] = __builtin_amdgcn_mfma_f32_16x16x32_bf16(af[m], bfr[n], acc[m][n], 0, 0, 0);
}

// K1: partial_b[256][256] (bf16) = sum over this block's 512-row N-chunk of v1[n][i]*v2[n][j]
__global__ __launch_bounds__(1024, 3) void k_gemm(const float* __restrict__ v1,
                                                  const float* __restrict__ v2,
                                                  unsigned short* __restrict__ part)
{
  __shared__ char sm[65536];   // buf0: A@0 B@16K ; buf1: A@32K B@48K  (BK=32, rows=64B)
  const int t    = threadIdx.x;
  const int b    = blockIdx.x;
  const int lane = t & 63, wid = t >> 6;
  const int di   = lane & 15, g = lane >> 4;
  const int wr   = wid >> 2, wc = wid & 3;
  const int i0   = wr * 64, j0 = wc * 64;   // 4x4 waves, 64x64 tile each
  const int rp   = wid;                     // staging: wave = row-pair of chunk
  const int c0   = lane * 4;                // 4-col group

  int offW[4], offA[4], offB[4];
#pragma unroll
  for (int m = 0; m < 4; ++m){ int i = c0 + m;         offW[m] = ((i << 6) + (rp << 2)) ^ swz(i); }
#pragma unroll
  for (int m = 0; m < 4; ++m){ int i = i0 + 16*m + di; offA[m] = ((i << 6) + (g << 4)) ^ swz(i); }
#pragma unroll
  for (int n = 0; n < 4; ++n){ int j = j0 + 16*n + di; offB[n] = ((j << 6) + (g << 4)) ^ swz(j); }

  f32x4 acc[4][4];
#pragma unroll
  for (int m = 0; m < 4; ++m)
#pragma unroll
    for (int n = 0; n < 4; ++n){ f32x4 z = {0.f,0.f,0.f,0.f}; acc[m][n] = z; }

  const long rowBase = (long)b * RPB;
  const float* pa = v1 + (rowBase + 2*rp) * KDIM + c0;
  const float* pb = v2 + (rowBase + 2*rp) * KDIM + c0;

  Stage sE, sO;                      // even-chunk / odd-chunk register sets
  stage_load(sE, pa, pb, 0);
  stage_load(sO, pa, pb, CH);
  stage_store(sE, sm, sm + 16384, offW);
  lds_barrier();

#pragma unroll 2
  for (int c = 0; c < NCH; ++c){
    const int cb = c & 1;
    char* Ac = sm + cb * 32768;        char* Bc = Ac + 16384;
    char* An = sm + (cb ^ 1) * 32768;  char* Bn = An + 16384;
    if (c + 2 < NCH){                         // issue loads for chunk c+2 first
      Stage& ld = cb ? sO : sE;               // (c+2)&1 == c&1
      stage_load(ld, pa, pb, (long)(c + 2) * CH);
    }
    if (c + 1 < NCH){                         // store chunk c+1 (compiler waits vmcnt(4):
      Stage& st = cb ? sE : sO;               //  chunk c+2's loads stay in flight)
      stage_store(st, An, Bn, offW);
    }
    compute_t(Ac, Bc, offA, offB, acc);
    lds_barrier();                            // lgkm-only: no vmcnt drain
  }

  unsigned short* op = part + (size_t)b * PN;
#pragma unroll
  for (int m = 0; m < 4; ++m)
#pragma unroll
    for (int n = 0; n < 4; ++n){
      const int i = i0 + 16*m + 4*g;
      const int j = j0 + 16*n + di;
#pragma unroll
      for (int r = 0; r < 4; ++r)
        op[(size_t)(i + r) * KDIM + j] = f2bf(acc[m][n][r]);
    }
}

// K2: P = sum_b part_b ; row sums r[gr] and (atomic) col sums c[j]
__global__ __launch_bounds__(1024) void k_reduce(const unsigned short* __restrict__ part,
                                                 float* __restrict__ P,
                                                 float* __restrict__ rsum,
                                                 float* __restrict__ csum)
{
  __shared__ float red[1024];
  const int gr = blockIdx.x;            // P row
  const int t  = threadIdx.x;
  const int j  = t & 255, q = t >> 8;   // 4-way split over partial buffers
  const int bpq = NB >> 2;
  float s = 0.f;
  const unsigned short* p = part + (size_t)(q * bpq) * PN + gr * KDIM + j;
  for (int b = 0; b < bpq; ++b) s += bf2f(p[(size_t)b * PN]);
  red[t] = s; __syncthreads();
  if (t < 512) red[t] += red[t + 512];
  __syncthreads();
  float v = 0.f;
  if (t < 256){
    v = red[t] + red[t + 256];
    P[gr * KDIM + t] = v;
    atomicAdd(&csum[t], v);
  }
  __syncthreads();
  red[t] = (t < 256) ? v : 0.f;
  __syncthreads();
  for (int st = 128; st > 0; st >>= 1){
    if (t < st) red[t] += red[t + st];
    __syncthreads();
  }
  if (t == 0) rsum[gr] = red[0];
}

// K3: S = sum r ; lm[i] = log((r_i + c_i)/(2S)) ; scal[0] = 1/(2S) ; zero out[0]
__global__ __launch_bounds__(256) void k_marg(const float* __restrict__ rsum,
                                              const float* __restrict__ csum,
                                              float* __restrict__ lm,
                                              float* __restrict__ scal,
                                              float* __restrict__ out)
{
  __shared__ float red[256];
  const int i = threadIdx.x;
  float ri = rsum[i];
  red[i] = ri; __syncthreads();
  for (int st = 128; st > 0; st >>= 1){
    if (i < st) red[i] += red[i + st];
    __syncthreads();
  }
  const float S = red[0];
  const float inv2S = 0.5f / S;
  float mi = (ri + csum[i]) * inv2S;
  mi = fmaxf(mi, 2.220446049250313e-16f);
  lm[i] = logf(mi);
  if (i == 0){ scal[0] = inv2S; out[0] = 0.f; }
}

// K4: loss = sum_ij -q*(log q - 10*(lm_i + lm_j)),  q = (P_ij + P_ji)/(2S)
// 128 blocks x 256 threads, one atomicAdd per block into out[0] (zeroed by k_marg)
__global__ __launch_bounds__(256) void k_loss(const float* __restrict__ P,
                                              const float* __restrict__ lm,
                                              const float* __restrict__ scal,
                                              float* __restrict__ out)
{
  __shared__ float red[256];
  const float inv2S = scal[0];
  float acc = 0.f;
  const int base = blockIdx.x * 512;
  for (int e = base + threadIdx.x; e < base + 512; e += 256){
    const int i = e >> 8, j = e & 255;
    float q = (P[i * KDIM + j] + P[j * KDIM + i]) * inv2S;
    q = fmaxf(q, 2.220446049250313e-16f);
    acc += -q * (logf(q) - 10.0f * (lm[i] + lm[j]));
  }
  red[threadIdx.x] = acc; __syncthreads();
  for (int st = 128; st > 0; st >>= 1){
    if (threadIdx.x < st) red[threadIdx.x] += red[threadIdx.x + st];
    __syncthreads();
  }
  if (threadIdx.x == 0) atomicAdd(out, red[0]);
}

extern "C" void kernel_launch(void* const* d_in, const int* in_sizes, int n_in,
                              void* d_out, int out_size, void* d_ws, size_t ws_size,
                              hipStream_t stream) {
  const float* v1 = (const float*)d_in[0];
  const float* v2 = (const float*)d_in[1];
  float* out = (float*)d_out;
  char*  wsc = (char*)d_ws;

  unsigned short* part = (unsigned short*)wsc;                 // NB*PN bf16 = 32 MB
  float* P    = (float*)(wsc + (size_t)NB * PN * 2);           // 256 KB
  float* rsum = P + PN;
  float* csum = rsum + 256;
  float* lm   = csum + 256;
  float* scal = lm + 256;

  hipMemsetAsync(csum, 0, 256 * sizeof(float), stream);
  k_gemm  <<<NB, 1024, 0, stream>>>(v1, v2, part);
  k_reduce<<<256, 1024, 0, stream>>>(part, P, rsum, csum);
  k_marg  <<<1, 256, 0, stream>>>(rsum, csum, lm, scal, out);
  k_loss  <<<128, 256, 0, stream>>>(P, lm, scal, out);
}

// Round 4
// 75.055 us; speedup vs baseline: 2.0678x; 1.4054x over previous
//
#include <hip/hip_runtime.h>
#include <hip/hip_bf16.h>

#define KDIM 256
#define NTOT 131072
#define PN   65536      // 256*256
#define NB   256        // split-K blocks
#define RPB  512        // rows per block = NTOT/NB
#define NCH  16         // chunks per block = RPB/32
#define CH   (32*KDIM)  // floats per chunk per matrix

typedef float f32x4 __attribute__((ext_vector_type(4)));
typedef __bf16 bf16x8 __attribute__((ext_vector_type(8)));

__device__ __forceinline__ unsigned short f2bf(float x){
  unsigned u = __float_as_uint(x);
  u += 0x7fffu + ((u >> 16) & 1u);   // round-to-nearest-even
  return (unsigned short)(u >> 16);
}
__device__ __forceinline__ unsigned pk2(float lo, float hi){
  return (unsigned)f2bf(lo) | ((unsigned)f2bf(hi) << 16);
}
__device__ __forceinline__ float bf2f(unsigned short u){
  return __uint_as_float((unsigned)u << 16);
}
// XOR swizzle on byte-bits 4..6 of a 64B-row layout
__device__ __forceinline__ int swz(int i){ return (((i >> 1) ^ (i >> 4)) & 7) << 4; }

struct Stage { f32x4 a0, a1, b0, b1; };   // 16 VGPRs only — one set, no spill

__device__ __forceinline__ void stage_load(Stage& s, const float* pa, const float* pb, long off){
  s.a0 = *(const f32x4*)(pa + off);
  s.a1 = *(const f32x4*)(pa + off + KDIM);
  s.b0 = *(const f32x4*)(pb + off);
  s.b1 = *(const f32x4*)(pb + off + KDIM);
}

__device__ __forceinline__ void stage_store(const Stage& s, char* As, char* Bs, const int* offW){
#pragma unroll
  for (int m = 0; m < 4; ++m){
    *(unsigned*)(As + offW[m]) = pk2(s.a0[m], s.a1[m]);
    *(unsigned*)(Bs + offW[m]) = pk2(s.b0[m], s.b1[m]);
  }
}

__device__ __forceinline__ void compute_t(const char* As, const char* Bs,
                                          const int* offA, const int* offB,
                                          f32x4 (&acc)[4][4])
{
  bf16x8 af[4], bfr[4];
#pragma unroll
  for (int m = 0; m < 4; ++m) af[m]  = *(const bf16x8*)(As + offA[m]);
#pragma unroll
  for (int n = 0; n < 4; ++n) bfr[n] = *(const bf16x8*)(Bs + offB[n]);
#pragma unroll
  for (int m = 0; m < 4; ++m)
#pragma unroll
    for (int n = 0; n < 4; ++n)
      acc[m][n] = __builtin_amdgcn_mfma_f32_16x16x32_bf16(af[m], bfr[n], acc[m][n], 0, 0, 0);
}

// K1: partial_b[256][256] (bf16) = sum over this block's 512-row N-chunk of v1[n][i]*v2[n][j]
__global__ __launch_bounds__(1024) void k_gemm(const float* __restrict__ v1,
                                               const float* __restrict__ v2,
                                               unsigned short* __restrict__ part)
{
  __shared__ char sm[65536];   // buf0: A@0 B@16K ; buf1: A@32K B@48K  (BK=32, rows=64B)
  const int t    = threadIdx.x;
  const int b    = blockIdx.x;
  const int lane = t & 63, wid = t >> 6;
  const int di   = lane & 15, g = lane >> 4;
  const int wr   = wid >> 2, wc = wid & 3;
  const int i0   = wr * 64, j0 = wc * 64;   // 4x4 waves, 64x64 tile each
  const int rp   = wid;                     // staging: wave = row-pair of chunk
  const int c0   = lane * 4;                // 4-col group

  int offW[4], offA[4], offB[4];
#pragma unroll
  for (int m = 0; m < 4; ++m){ int i = c0 + m;         offW[m] = ((i << 6) + (rp << 2)) ^ swz(i); }
#pragma unroll
  for (int m = 0; m < 4; ++m){ int i = i0 + 16*m + di; offA[m] = ((i << 6) + (g << 4)) ^ swz(i); }
#pragma unroll
  for (int n = 0; n < 4; ++n){ int j = j0 + 16*n + di; offB[n] = ((j << 6) + (g << 4)) ^ swz(j); }

  f32x4 acc[4][4];
#pragma unroll
  for (int m = 0; m < 4; ++m)
#pragma unroll
    for (int n = 0; n < 4; ++n){ f32x4 z = {0.f,0.f,0.f,0.f}; acc[m][n] = z; }

  const long rowBase = (long)b * RPB;
  const float* pa = v1 + (rowBase + 2*rp) * KDIM + c0;
  const float* pb = v2 + (rowBase + 2*rp) * KDIM + c0;

  Stage s;                                   // single staging set (16 regs live)
  stage_load(s, pa, pb, 0);
  stage_store(s, sm, sm + 16384, offW);      // auto vmcnt wait on own loads
  asm volatile("s_waitcnt lgkmcnt(0)");      // ds_writes visible (lgkm only)
  __builtin_amdgcn_sched_barrier(0);
  __builtin_amdgcn_s_barrier();              // raw barrier: no vmcnt drain

#pragma unroll 1
  for (int c = 0; c < NCH; ++c){
    const int cb = c & 1;
    char* Ac = sm + cb * 32768;        char* Bc = Ac + 16384;
    char* An = sm + (cb ^ 1) * 32768;  char* Bn = An + 16384;
    if (c + 1 < NCH){
      stage_load(s, pa, pb, (long)(c + 1) * CH);  // issue next chunk's 4 loads
      __builtin_amdgcn_sched_barrier(0);          // PIN: loads stay before compute
    }
    compute_t(Ac, Bc, offA, offB, acc);           // ~full chunk of MFMA hides latency
    __builtin_amdgcn_sched_barrier(0);            // store (and its vmcnt wait) after compute
    if (c + 1 < NCH){
      stage_store(s, An, Bn, offW);               // auto counted vmcnt before first use
    }
    asm volatile("s_waitcnt lgkmcnt(0)");         // LDS writes visible to all waves
    __builtin_amdgcn_sched_barrier(0);
    __builtin_amdgcn_s_barrier();                 // raw: global loads may stay in flight
  }

  unsigned short* op = part + (size_t)b * PN;
#pragma unroll
  for (int m = 0; m < 4; ++m)
#pragma unroll
    for (int n = 0; n < 4; ++n){
      const int i = i0 + 16*m + 4*g;
      const int j = j0 + 16*n + di;
#pragma unroll
      for (int r = 0; r < 4; ++r)
        op[(size_t)(i + r) * KDIM + j] = f2bf(acc[m][n][r]);
    }
}

// K2: P = sum_b part_b ; row sums r[gr] and (atomic) col sums c[j]
__global__ __launch_bounds__(1024) void k_reduce(const unsigned short* __restrict__ part,
                                                 float* __restrict__ P,
                                                 float* __restrict__ rsum,
                                                 float* __restrict__ csum)
{
  __shared__ float red[1024];
  const int gr = blockIdx.x;            // P row
  const int t  = threadIdx.x;
  const int j  = t & 255, q = t >> 8;   // 4-way split over partial buffers
  const int bpq = NB >> 2;
  float s = 0.f;
  const unsigned short* p = part + (size_t)(q * bpq) * PN + gr * KDIM + j;
  for (int b = 0; b < bpq; ++b) s += bf2f(p[(size_t)b * PN]);
  red[t] = s; __syncthreads();
  if (t < 512) red[t] += red[t + 512];
  __syncthreads();
  float v = 0.f;
  if (t < 256){
    v = red[t] + red[t + 256];
    P[gr * KDIM + t] = v;
    atomicAdd(&csum[t], v);
  }
  __syncthreads();
  red[t] = (t < 256) ? v : 0.f;
  __syncthreads();
  for (int st = 128; st > 0; st >>= 1){
    if (t < st) red[t] += red[t + st];
    __syncthreads();
  }
  if (t == 0) rsum[gr] = red[0];
}

// K3: S = sum r ; lm[i] = log((r_i + c_i)/(2S)) ; scal[0] = 1/(2S) ; zero out[0]
__global__ __launch_bounds__(256) void k_marg(const float* __restrict__ rsum,
                                              const float* __restrict__ csum,
                                              float* __restrict__ lm,
                                              float* __restrict__ scal,
                                              float* __restrict__ out)
{
  __shared__ float red[256];
  const int i = threadIdx.x;
  float ri = rsum[i];
  red[i] = ri; __syncthreads();
  for (int st = 128; st > 0; st >>= 1){
    if (i < st) red[i] += red[i + st];
    __syncthreads();
  }
  const float S = red[0];
  const float inv2S = 0.5f / S;
  float mi = (ri + csum[i]) * inv2S;
  mi = fmaxf(mi, 2.220446049250313e-16f);
  lm[i] = logf(mi);
  if (i == 0){ scal[0] = inv2S; out[0] = 0.f; }
}

// K4: loss = sum_ij -q*(log q - 10*(lm_i + lm_j)),  q = (P_ij + P_ji)/(2S)
// 128 blocks x 256 threads, one atomicAdd per block into out[0] (zeroed by k_marg)
__global__ __launch_bounds__(256) void k_loss(const float* __restrict__ P,
                                              const float* __restrict__ lm,
                                              const float* __restrict__ scal,
                                              float* __restrict__ out)
{
  __shared__ float red[256];
  const float inv2S = scal[0];
  float acc = 0.f;
  const int base = blockIdx.x * 512;
  for (int e = base + threadIdx.x; e < base + 512; e += 256){
    const int i = e >> 8, j = e & 255;
    float q = (P[i * KDIM + j] + P[j * KDIM + i]) * inv2S;
    q = fmaxf(q, 2.220446049250313e-16f);
    acc += -q * (logf(q) - 10.0f * (lm[i] + lm[j]));
  }
  red[threadIdx.x] = acc; __syncthreads();
  for (int st = 128; st > 0; st >>= 1){
    if (threadIdx.x < st) red[threadIdx.x] += red[threadIdx.x + st];
    __syncthreads();
  }
  if (threadIdx.x == 0) atomicAdd(out, red[0]);
}

extern "C" void kernel_launch(void* const* d_in, const int* in_sizes, int n_in,
                              void* d_out, int out_size, void* d_ws, size_t ws_size,
                              hipStream_t stream) {
  const float* v1 = (const float*)d_in[0];
  const float* v2 = (const float*)d_in[1];
  float* out = (float*)d_out;
  char*  wsc = (char*)d_ws;

  unsigned short* part = (unsigned short*)wsc;                 // NB*PN bf16 = 32 MB
  float* P    = (float*)(wsc + (size_t)NB * PN * 2);           // 256 KB
  float* rsum = P + PN;
  float* csum = rsum + 256;
  float* lm   = csum + 256;
  float* scal = lm + 256;

  hipMemsetAsync(csum, 0, 256 * sizeof(float), stream);
  k_gemm  <<<NB, 1024, 0, stream>>>(v1, v2, part);
  k_reduce<<<256, 1024, 0, stream>>>(part, P, rsum, csum);
  k_marg  <<<1, 256, 0, stream>>>(rsum, csum, lm, scal, out);
  k_loss  <<<128, 256, 0, stream>>>(P, lm, scal, out);
}